// Round 2
// baseline (631.603 us; speedup 1.0000x reference)
//
#include <hip/hip_runtime.h>

typedef short s8v __attribute__((ext_vector_type(8)));   // 8 x bf16 bits
typedef float f4v __attribute__((ext_vector_type(4)));

#define NB 65536
#define BT 32
#define STR 264            // padded ushort stride for LDS tiles
#define OSTR 260           // padded float stride for output staging
#define PW_ELEMS 786432
#define PG0_OFF  786432
#define PG1T0_OFF 790528
#define PG1T1_OFF 794624
#define TOTAL_PACK 798720

__device__ __forceinline__ unsigned short f2bf(float f) {
  unsigned u = __float_as_uint(f);
  u += 0x7FFF + ((u >> 16) & 1);           // round-to-nearest-even
  return (unsigned short)(u >> 16);
}

__global__ void pack_weights(const float* __restrict__ we_task,
                             const float* __restrict__ we_share,
                             const float* __restrict__ wg_task,
                             const float* __restrict__ wg_share,
                             unsigned short* __restrict__ ws) {
  int i = blockIdx.x * 256 + threadIdx.x;
  if (i >= TOTAL_PACK) return;
  float v = 0.f;
  if (i < PW_ELEMS) {
    int j = i & 7;
    int t = i >> 3;
    int lane = t & 63; t >>= 6;
    int kc = t & 7;    t >>= 3;
    int nt = t & 15;   t >>= 4;
    int lvl = t / 6, e = t % 6;
    int d = kc * 32 + (lane >> 4) * 8 + j;
    int u = nt * 16 + (lane & 15);
    if (e < 4) v = we_task[((lvl * 4 + e) * 256 + d) * 256 + u];
    else       v = we_share[((lvl * 2 + (e - 4)) * 256 + d) * 256 + u];
  } else {
    int gi = i - PW_ELEMS;
    int which = gi >> 12;
    int r = gi & 4095;
    int j = r & 7;
    int lane = (r >> 3) & 63;
    int kc = r >> 9;
    int d = kc * 32 + (lane >> 4) * 8 + j;
    int n = lane & 15;
    if (which == 0) {
      if (n < 4)       v = wg_task[0 * 1024 + d * 4 + n];
      else if (n < 8)  v = wg_task[1 * 1024 + d * 4 + (n - 4)];
      else if (n < 14) v = wg_share[d * 6 + (n - 8)];
    } else if (which == 1) {
      if (n < 4) v = wg_task[2 * 1024 + d * 4 + n];
    } else {
      if (n < 4) v = wg_task[3 * 1024 + d * 4 + n];
    }
  }
  ws[i] = f2bf(v);
}

__device__ __forceinline__ s8v ld_af(const unsigned short* Ab, int m, int kc,
                                     int col, int rq) {
  return *(const s8v*)&Ab[(m * 16 + col) * STR + kc * 32 + rq * 8];
}

__launch_bounds__(512, 4)
__global__ void ple_fused(const float* __restrict__ x,
                          const float* __restrict__ be_task,
                          const float* __restrict__ be_share,
                          const float* __restrict__ bg_task,
                          const float* __restrict__ bg_share,
                          const unsigned short* __restrict__ ws,
                          float* __restrict__ out) {
  __shared__ unsigned short A0[BT * STR];       // x at lvl0; shared-branch input at lvl1
  __shared__ unsigned short A1[2][BT * STR];    // lvl1 task inputs; output staging at end
  __shared__ float g_lds[BT * 16];
  __shared__ float bias_lds[6 * 256];

  const int tid  = threadIdx.x;
  const int lane = tid & 63;
  const int wave = tid >> 6;
  const int col  = lane & 15;
  const int rq   = lane >> 4;
  const int r0   = blockIdx.x * BT;

  // ---- stage x -> bf16 LDS, load lvl0 biases ----
  {
    const float* xb = x + (long)r0 * 256;
#pragma unroll
    for (int i = 0; i < 4; ++i) {
      int f = tid + i * 512;            // 2048 float4 total (32 rows x 64)
      int row = f >> 6, c4 = f & 63;
      const float4 v = *(const float4*)(xb + row * 256 + c4 * 4);
      unsigned lo = ((unsigned)f2bf(v.y) << 16) | f2bf(v.x);
      unsigned hi = ((unsigned)f2bf(v.w) << 16) | f2bf(v.z);
      *(uint2*)&A0[row * STR + c4 * 4] = make_uint2(lo, hi);
    }
    for (int idx = tid; idx < 1536; idx += 512)
      bias_lds[idx] = (idx < 1024) ? be_task[idx] : be_share[idx - 1024];
  }
  __syncthreads();

  // ---- level-0 gate logits (waves 0..1, one m-tile each) ----
  if (wave < 2) {
    const int m = wave;
    f4v ag = {0.f, 0.f, 0.f, 0.f};
    for (int kc = 0; kc < 8; ++kc) {
      s8v af = ld_af(A0, m, kc, col, rq);
      s8v bg = *(const s8v*)&ws[PG0_OFF + (kc * 64 + lane) * 8];
      ag = __builtin_amdgcn_mfma_f32_16x16x32_bf16(af, bg, ag, 0, 0, 0);
    }
#pragma unroll
    for (int r = 0; r < 4; ++r)
      g_lds[(m * 16 + rq * 4 + r) * 16 + col] = ag[r];
  }
  __syncthreads();

  // ---- level-0 softmaxes (one thread per row) ----
  if (tid < 32) {
    float* g = &g_lds[tid * 16];
    {
      float a0 = g[0] + bg_task[0], a1 = g[1] + bg_task[1];
      float a2 = g[2] + bg_task[2], a3 = g[3] + bg_task[3];
      float mx = fmaxf(fmaxf(a0, a1), fmaxf(a2, a3));
      float e0 = __expf(a0 - mx), e1 = __expf(a1 - mx);
      float e2 = __expf(a2 - mx), e3 = __expf(a3 - mx);
      float inv = 1.f / (e0 + e1 + e2 + e3);
      g[0] = e0 * inv; g[1] = e1 * inv; g[2] = e2 * inv; g[3] = e3 * inv;
    }
    {
      float a0 = g[4] + bg_task[4], a1 = g[5] + bg_task[5];
      float a2 = g[6] + bg_task[6], a3 = g[7] + bg_task[7];
      float mx = fmaxf(fmaxf(a0, a1), fmaxf(a2, a3));
      float e0 = __expf(a0 - mx), e1 = __expf(a1 - mx);
      float e2 = __expf(a2 - mx), e3 = __expf(a3 - mx);
      float inv = 1.f / (e0 + e1 + e2 + e3);
      g[4] = e0 * inv; g[5] = e1 * inv; g[6] = e2 * inv; g[7] = e3 * inv;
    }
    {
      float a[6], mx = -1e30f;
#pragma unroll
      for (int k = 0; k < 6; ++k) { a[k] = g[8 + k] + bg_share[k]; mx = fmaxf(mx, a[k]); }
      float s = 0.f;
#pragma unroll
      for (int k = 0; k < 6; ++k) { a[k] = __expf(a[k] - mx); s += a[k]; }
      float inv = 1.f / s;
#pragma unroll
      for (int k = 0; k < 6; ++k) g[8 + k] = a[k] * inv;
    }
  }
  __syncthreads();

  // ---- level-0 experts + combine ----
  float v2[2][8];
#pragma unroll
  for (int q = 0; q < 2; ++q) {
    const int nt = wave + q * 8;      // adjacent u-tiles across waves (concurrent stores)
    f4v acc[2][6];
#pragma unroll
    for (int m = 0; m < 2; ++m)
#pragma unroll
      for (int e = 0; e < 6; ++e) acc[m][e] = (f4v){0.f, 0.f, 0.f, 0.f};

    const unsigned short* pw = ws + nt * 4096;   // lvl0: e*65536 + nt*4096
    s8v bfc[6];
#pragma unroll
    for (int e = 0; e < 6; ++e)
      bfc[e] = *(const s8v*)&pw[e * 65536 + lane * 8];
#pragma unroll
    for (int kc = 0; kc < 8; ++kc) {
      s8v bfn[6];
      if (kc < 7) {
#pragma unroll
        for (int e = 0; e < 6; ++e)
          bfn[e] = *(const s8v*)&pw[e * 65536 + ((kc + 1) * 64 + lane) * 8];
      }
      s8v af[2];
#pragma unroll
      for (int m = 0; m < 2; ++m) af[m] = ld_af(A0, m, kc, col, rq);
#pragma unroll
      for (int m = 0; m < 2; ++m)
#pragma unroll
        for (int e = 0; e < 6; ++e)
          acc[m][e] = __builtin_amdgcn_mfma_f32_16x16x32_bf16(af[m], bfc[e], acc[m][e], 0, 0, 0);
#pragma unroll
      for (int e = 0; e < 6; ++e) bfc[e] = bfn[e];
    }

    const int u = nt * 16 + col;
    float bz[6];
#pragma unroll
    for (int e = 0; e < 6; ++e) bz[e] = bias_lds[e * 256 + u];
#pragma unroll
    for (int m = 0; m < 2; ++m) {
#pragma unroll
      for (int r = 0; r < 4; ++r) {
        int row = m * 16 + rq * 4 + r;
        const float* gr = &g_lds[row * 16];
        f4v ga = *(const f4v*)&gr[0];
        f4v gb = *(const f4v*)&gr[4];
        f4v gc = *(const f4v*)&gr[8];
        float gs4 = gr[12], gs5 = gr[13];
        float E0 = fmaxf(acc[m][0][r] + bz[0], 0.f);
        float E1 = fmaxf(acc[m][1][r] + bz[1], 0.f);
        float E2 = fmaxf(acc[m][2][r] + bz[2], 0.f);
        float E3 = fmaxf(acc[m][3][r] + bz[3], 0.f);
        float E4 = fmaxf(acc[m][4][r] + bz[4], 0.f);
        float E5 = fmaxf(acc[m][5][r] + bz[5], 0.f);
        float o0 = ga[0] * E0 + ga[1] * E1 + ga[2] * E4 + ga[3] * E5;
        float o1 = gb[0] * E2 + gb[1] * E3 + gb[2] * E4 + gb[3] * E5;
        float o2 = gc[0] * E0 + gc[1] * E1 + gc[2] * E2 + gc[3] * E3 + gs4 * E4 + gs5 * E5;
        A1[0][row * STR + u] = f2bf(o0);
        A1[1][row * STR + u] = f2bf(o1);
        v2[q][m * 4 + r] = o2;
      }
    }
  }
  __syncthreads();

  // ---- shared-branch output -> A0 (reuse); load lvl1 biases ----
#pragma unroll
  for (int q = 0; q < 2; ++q) {
    const int u = (wave + q * 8) * 16 + col;
#pragma unroll
    for (int m = 0; m < 2; ++m)
#pragma unroll
      for (int r = 0; r < 4; ++r)
        A0[(m * 16 + rq * 4 + r) * STR + u] = f2bf(v2[q][m * 4 + r]);
  }
  for (int idx = tid; idx < 1536; idx += 512)
    bias_lds[idx] = (idx < 1024) ? be_task[1024 + idx] : be_share[512 + idx - 1024];
  __syncthreads();

  // ---- level-1 gate logits (4 waves: m = wave>>1, t = wave&1) ----
  if (wave < 4) {
    const int m = wave >> 1;
    const int t = wave & 1;
    const unsigned short* pg = ws + (t ? PG1T1_OFF : PG1T0_OFF);
    f4v ag = {0.f, 0.f, 0.f, 0.f};
    for (int kc = 0; kc < 8; ++kc) {
      s8v af = ld_af(A1[t], m, kc, col, rq);
      s8v bg = *(const s8v*)&pg[(kc * 64 + lane) * 8];
      ag = __builtin_amdgcn_mfma_f32_16x16x32_bf16(af, bg, ag, 0, 0, 0);
    }
    if (col < 4) {
#pragma unroll
      for (int r = 0; r < 4; ++r)
        g_lds[(m * 16 + rq * 4 + r) * 16 + t * 4 + col] = ag[r];
    }
  }
  __syncthreads();

  // ---- level-1 softmaxes ----
  if (tid < 32) {
    float* g = &g_lds[tid * 16];
    {
      float a0 = g[0] + bg_task[8],  a1 = g[1] + bg_task[9];
      float a2 = g[2] + bg_task[10], a3 = g[3] + bg_task[11];
      float mx = fmaxf(fmaxf(a0, a1), fmaxf(a2, a3));
      float e0 = __expf(a0 - mx), e1 = __expf(a1 - mx);
      float e2 = __expf(a2 - mx), e3 = __expf(a3 - mx);
      float inv = 1.f / (e0 + e1 + e2 + e3);
      g[0] = e0 * inv; g[1] = e1 * inv; g[2] = e2 * inv; g[3] = e3 * inv;
    }
    {
      float a0 = g[4] + bg_task[12], a1 = g[5] + bg_task[13];
      float a2 = g[6] + bg_task[14], a3 = g[7] + bg_task[15];
      float mx = fmaxf(fmaxf(a0, a1), fmaxf(a2, a3));
      float e0 = __expf(a0 - mx), e1 = __expf(a1 - mx);
      float e2 = __expf(a2 - mx), e3 = __expf(a3 - mx);
      float inv = 1.f / (e0 + e1 + e2 + e3);
      g[4] = e0 * inv; g[5] = e1 * inv; g[6] = e2 * inv; g[7] = e3 * inv;
    }
  }
  __syncthreads();

  // ---- level-1 experts + combine (results held in registers) ----
  float o0r[2][2][4], o1r[2][2][4];
#pragma unroll
  for (int q = 0; q < 2; ++q) {
    const int nt = wave + q * 8;
    f4v acc[2][6];
#pragma unroll
    for (int m = 0; m < 2; ++m)
#pragma unroll
      for (int e = 0; e < 6; ++e) acc[m][e] = (f4v){0.f, 0.f, 0.f, 0.f};

    const unsigned short* pw = ws + 6 * 65536 + nt * 4096;  // lvl1 base
    s8v bfc[6];
#pragma unroll
    for (int e = 0; e < 6; ++e)
      bfc[e] = *(const s8v*)&pw[e * 65536 + lane * 8];
#pragma unroll
    for (int kc = 0; kc < 8; ++kc) {
      s8v bfn[6];
      if (kc < 7) {
#pragma unroll
        for (int e = 0; e < 6; ++e)
          bfn[e] = *(const s8v*)&pw[e * 65536 + ((kc + 1) * 64 + lane) * 8];
      }
      s8v a0f[2], a1f[2], a2f[2];
#pragma unroll
      for (int m = 0; m < 2; ++m) {
        a0f[m] = ld_af(A1[0], m, kc, col, rq);
        a1f[m] = ld_af(A1[1], m, kc, col, rq);
        a2f[m] = ld_af(A0,    m, kc, col, rq);
      }
#pragma unroll
      for (int m = 0; m < 2; ++m) {
        acc[m][0] = __builtin_amdgcn_mfma_f32_16x16x32_bf16(a0f[m], bfc[0], acc[m][0], 0, 0, 0);
        acc[m][1] = __builtin_amdgcn_mfma_f32_16x16x32_bf16(a0f[m], bfc[1], acc[m][1], 0, 0, 0);
        acc[m][2] = __builtin_amdgcn_mfma_f32_16x16x32_bf16(a1f[m], bfc[2], acc[m][2], 0, 0, 0);
        acc[m][3] = __builtin_amdgcn_mfma_f32_16x16x32_bf16(a1f[m], bfc[3], acc[m][3], 0, 0, 0);
        acc[m][4] = __builtin_amdgcn_mfma_f32_16x16x32_bf16(a2f[m], bfc[4], acc[m][4], 0, 0, 0);
        acc[m][5] = __builtin_amdgcn_mfma_f32_16x16x32_bf16(a2f[m], bfc[5], acc[m][5], 0, 0, 0);
      }
#pragma unroll
      for (int e = 0; e < 6; ++e) bfc[e] = bfn[e];
    }

    const int u = nt * 16 + col;
    float bz[6];
#pragma unroll
    for (int e = 0; e < 6; ++e) bz[e] = bias_lds[e * 256 + u];
#pragma unroll
    for (int m = 0; m < 2; ++m) {
#pragma unroll
      for (int r = 0; r < 4; ++r) {
        const int row = m * 16 + rq * 4 + r;
        const float* gr = &g_lds[row * 16];
        f4v ga = *(const f4v*)&gr[0];
        f4v gb = *(const f4v*)&gr[4];
        float E0 = fmaxf(acc[m][0][r] + bz[0], 0.f);
        float E1 = fmaxf(acc[m][1][r] + bz[1], 0.f);
        float E2 = fmaxf(acc[m][2][r] + bz[2], 0.f);
        float E3 = fmaxf(acc[m][3][r] + bz[3], 0.f);
        float E4 = fmaxf(acc[m][4][r] + bz[4], 0.f);
        float E5 = fmaxf(acc[m][5][r] + bz[5], 0.f);
        o0r[q][m][r] = ga[0] * E0 + ga[1] * E1 + ga[2] * E4 + ga[3] * E5;
        o1r[q][m][r] = gb[0] * E2 + gb[1] * E3 + gb[2] * E4 + gb[3] * E5;
      }
    }
  }

  // ---- staged, fully-coalesced output stores (A0/A1 are dead now) ----
  // stage buffer: 32 rows x OSTR floats = 33280 B, aliases A1 (33792 B)
  float* stage = (float*)&A1[0][0];
  __syncthreads();                       // all waves done reading A0/A1
#pragma unroll
  for (int q = 0; q < 2; ++q) {
    const int u = (wave + q * 8) * 16 + col;
#pragma unroll
    for (int m = 0; m < 2; ++m)
#pragma unroll
      for (int r = 0; r < 4; ++r)
        stage[(m * 16 + rq * 4 + r) * OSTR + u] = o0r[q][m][r];
  }
  __syncthreads();
  {
    float* ob = out + (long)r0 * 256;
#pragma unroll
    for (int i = 0; i < 4; ++i) {
      int f = tid + i * 512;             // 2048 float4 (32 rows x 64)
      int row = f >> 6, c4 = f & 63;
      float4 v = *(const float4*)&stage[row * OSTR + c4 * 4];
      *(float4*)(ob + row * 256 + c4 * 4) = v;
    }
  }
  __syncthreads();
#pragma unroll
  for (int q = 0; q < 2; ++q) {
    const int u = (wave + q * 8) * 16 + col;
#pragma unroll
    for (int m = 0; m < 2; ++m)
#pragma unroll
      for (int r = 0; r < 4; ++r)
        stage[(m * 16 + rq * 4 + r) * OSTR + u] = o1r[q][m][r];
  }
  __syncthreads();
  {
    float* ob = out + 16777216L + (long)r0 * 256;
#pragma unroll
    for (int i = 0; i < 4; ++i) {
      int f = tid + i * 512;
      int row = f >> 6, c4 = f & 63;
      float4 v = *(const float4*)&stage[row * OSTR + c4 * 4];
      *(float4*)(ob + row * 256 + c4 * 4) = v;
    }
  }
}

extern "C" void kernel_launch(void* const* d_in, const int* in_sizes, int n_in,
                              void* d_out, int out_size, void* d_ws, size_t ws_size,
                              hipStream_t stream) {
  const float* x        = (const float*)d_in[0];
  const float* we_task  = (const float*)d_in[1];
  const float* be_task  = (const float*)d_in[2];
  const float* we_share = (const float*)d_in[3];
  const float* be_share = (const float*)d_in[4];
  const float* wg_task  = (const float*)d_in[5];
  const float* bg_task  = (const float*)d_in[6];
  const float* wg_share = (const float*)d_in[7];
  const float* bg_share = (const float*)d_in[8];
  unsigned short* ws = (unsigned short*)d_ws;
  float* out = (float*)d_out;

  hipLaunchKernelGGL(pack_weights, dim3((TOTAL_PACK + 255) / 256), dim3(256), 0, stream,
                     we_task, we_share, wg_task, wg_share, ws);
  hipLaunchKernelGGL(ple_fused, dim3(NB / BT), dim3(512), 0, stream,
                     x, be_task, be_share, bg_task, bg_share, ws, out);
}

// Round 3
// 391.389 us; speedup vs baseline: 1.6137x; 1.6137x over previous
//
#include <hip/hip_runtime.h>

typedef short s8v __attribute__((ext_vector_type(8)));   // 8 x bf16 bits
typedef float f4v __attribute__((ext_vector_type(4)));

#define NB 65536
#define BT 32
#define STR 264            // padded ushort stride for LDS tiles
#define PW_ELEMS 786432
#define PG0_OFF  786432
#define PG1T0_OFF 790528
#define PG1T1_OFF 794624
#define TOTAL_PACK 798720

__device__ __forceinline__ unsigned short f2bf(float f) {
  unsigned u = __float_as_uint(f);
  u += 0x7FFF + ((u >> 16) & 1);           // round-to-nearest-even
  return (unsigned short)(u >> 16);
}

__global__ void pack_weights(const float* __restrict__ we_task,
                             const float* __restrict__ we_share,
                             const float* __restrict__ wg_task,
                             const float* __restrict__ wg_share,
                             unsigned short* __restrict__ ws) {
  int i = blockIdx.x * 256 + threadIdx.x;
  if (i >= TOTAL_PACK) return;
  float v = 0.f;
  if (i < PW_ELEMS) {
    int j = i & 7;
    int t = i >> 3;
    int lane = t & 63; t >>= 6;
    int kc = t & 7;    t >>= 3;
    int nt = t & 15;   t >>= 4;
    int lvl = t / 6, e = t % 6;
    int d = kc * 32 + (lane >> 4) * 8 + j;
    int u = nt * 16 + (lane & 15);
    if (e < 4) v = we_task[((lvl * 4 + e) * 256 + d) * 256 + u];
    else       v = we_share[((lvl * 2 + (e - 4)) * 256 + d) * 256 + u];
  } else {
    int gi = i - PW_ELEMS;
    int which = gi >> 12;
    int r = gi & 4095;
    int j = r & 7;
    int lane = (r >> 3) & 63;
    int kc = r >> 9;
    int d = kc * 32 + (lane >> 4) * 8 + j;
    int n = lane & 15;
    if (which == 0) {
      if (n < 4)       v = wg_task[0 * 1024 + d * 4 + n];
      else if (n < 8)  v = wg_task[1 * 1024 + d * 4 + (n - 4)];
      else if (n < 14) v = wg_share[d * 6 + (n - 8)];
    } else if (which == 1) {
      if (n < 4) v = wg_task[2 * 1024 + d * 4 + n];
    } else {
      if (n < 4) v = wg_task[3 * 1024 + d * 4 + n];
    }
  }
  ws[i] = f2bf(v);
}

__device__ __forceinline__ s8v ld_af(const unsigned short* Ab, int m, int kc,
                                     int col, int rq) {
  return *(const s8v*)&Ab[(m * 16 + col) * STR + kc * 32 + rq * 8];
}

__launch_bounds__(512, 2)
__global__ void ple_fused(const float* __restrict__ x,
                          const float* __restrict__ be_task,
                          const float* __restrict__ be_share,
                          const float* __restrict__ bg_task,
                          const float* __restrict__ bg_share,
                          const unsigned short* __restrict__ ws,
                          float* __restrict__ out) {
  __shared__ unsigned short A0[BT * STR];       // x at lvl0; shared-branch input at lvl1
  __shared__ unsigned short A1[2][BT * STR];    // lvl1 task inputs
  __shared__ float g_lds[BT * 16];
  __shared__ float bias_lds[6 * 256];

  const int tid  = threadIdx.x;
  const int lane = tid & 63;
  const int wave = tid >> 6;
  const int col  = lane & 15;
  const int rq   = lane >> 4;
  const int r0   = blockIdx.x * BT;

  // ---- stage x -> bf16 LDS, load lvl0 biases ----
  {
    const float* xb = x + (long)r0 * 256;
#pragma unroll
    for (int i = 0; i < 4; ++i) {
      int f = tid + i * 512;            // 2048 float4 total (32 rows x 64)
      int row = f >> 6, c4 = f & 63;
      const float4 v = *(const float4*)(xb + row * 256 + c4 * 4);
      unsigned lo = ((unsigned)f2bf(v.y) << 16) | f2bf(v.x);
      unsigned hi = ((unsigned)f2bf(v.w) << 16) | f2bf(v.z);
      *(uint2*)&A0[row * STR + c4 * 4] = make_uint2(lo, hi);
    }
    for (int idx = tid; idx < 1536; idx += 512)
      bias_lds[idx] = (idx < 1024) ? be_task[idx] : be_share[idx - 1024];
  }
  __syncthreads();

  // ---- level-0 gate logits (waves 0..1, one m-tile each) ----
  if (wave < 2) {
    const int m = wave;
    f4v ag = {0.f, 0.f, 0.f, 0.f};
    for (int kc = 0; kc < 8; ++kc) {
      s8v af = ld_af(A0, m, kc, col, rq);
      s8v bg = *(const s8v*)&ws[PG0_OFF + (kc * 64 + lane) * 8];
      ag = __builtin_amdgcn_mfma_f32_16x16x32_bf16(af, bg, ag, 0, 0, 0);
    }
#pragma unroll
    for (int r = 0; r < 4; ++r)
      g_lds[(m * 16 + rq * 4 + r) * 16 + col] = ag[r];
  }
  __syncthreads();

  // ---- level-0 softmaxes (one thread per row) ----
  if (tid < 32) {
    float* g = &g_lds[tid * 16];
    {
      float a0 = g[0] + bg_task[0], a1 = g[1] + bg_task[1];
      float a2 = g[2] + bg_task[2], a3 = g[3] + bg_task[3];
      float mx = fmaxf(fmaxf(a0, a1), fmaxf(a2, a3));
      float e0 = __expf(a0 - mx), e1 = __expf(a1 - mx);
      float e2 = __expf(a2 - mx), e3 = __expf(a3 - mx);
      float inv = 1.f / (e0 + e1 + e2 + e3);
      g[0] = e0 * inv; g[1] = e1 * inv; g[2] = e2 * inv; g[3] = e3 * inv;
    }
    {
      float a0 = g[4] + bg_task[4], a1 = g[5] + bg_task[5];
      float a2 = g[6] + bg_task[6], a3 = g[7] + bg_task[7];
      float mx = fmaxf(fmaxf(a0, a1), fmaxf(a2, a3));
      float e0 = __expf(a0 - mx), e1 = __expf(a1 - mx);
      float e2 = __expf(a2 - mx), e3 = __expf(a3 - mx);
      float inv = 1.f / (e0 + e1 + e2 + e3);
      g[4] = e0 * inv; g[5] = e1 * inv; g[6] = e2 * inv; g[7] = e3 * inv;
    }
    {
      float a[6], mx = -1e30f;
#pragma unroll
      for (int k = 0; k < 6; ++k) { a[k] = g[8 + k] + bg_share[k]; mx = fmaxf(mx, a[k]); }
      float s = 0.f;
#pragma unroll
      for (int k = 0; k < 6; ++k) { a[k] = __expf(a[k] - mx); s += a[k]; }
      float inv = 1.f / s;
#pragma unroll
      for (int k = 0; k < 6; ++k) g[8 + k] = a[k] * inv;
    }
  }
  __syncthreads();

  // ---- level-0 experts + combine ----
  float v2[2][8];
#pragma unroll
  for (int q = 0; q < 2; ++q) {
    const int nt = wave + q * 8;      // adjacent u-tiles across waves (concurrent stores)
    f4v acc[2][6];
#pragma unroll
    for (int m = 0; m < 2; ++m)
#pragma unroll
      for (int e = 0; e < 6; ++e) acc[m][e] = (f4v){0.f, 0.f, 0.f, 0.f};

    const unsigned short* pw = ws + nt * 4096;   // lvl0: e*65536 + nt*4096
    s8v bfc[6];
#pragma unroll
    for (int e = 0; e < 6; ++e)
      bfc[e] = *(const s8v*)&pw[e * 65536 + lane * 8];
#pragma unroll
    for (int kc = 0; kc < 8; ++kc) {
      s8v bfn[6];
      if (kc < 7) {
#pragma unroll
        for (int e = 0; e < 6; ++e)
          bfn[e] = *(const s8v*)&pw[e * 65536 + ((kc + 1) * 64 + lane) * 8];
      }
      s8v af[2];
#pragma unroll
      for (int m = 0; m < 2; ++m) af[m] = ld_af(A0, m, kc, col, rq);
#pragma unroll
      for (int m = 0; m < 2; ++m)
#pragma unroll
        for (int e = 0; e < 6; ++e)
          acc[m][e] = __builtin_amdgcn_mfma_f32_16x16x32_bf16(af[m], bfc[e], acc[m][e], 0, 0, 0);
#pragma unroll
      for (int e = 0; e < 6; ++e) bfc[e] = bfn[e];
    }

    const int u = nt * 16 + col;
    float bz[6];
#pragma unroll
    for (int e = 0; e < 6; ++e) bz[e] = bias_lds[e * 256 + u];
#pragma unroll
    for (int m = 0; m < 2; ++m) {
#pragma unroll
      for (int r = 0; r < 4; ++r) {
        int row = m * 16 + rq * 4 + r;
        const float* gr = &g_lds[row * 16];
        f4v ga = *(const f4v*)&gr[0];
        f4v gb = *(const f4v*)&gr[4];
        f4v gc = *(const f4v*)&gr[8];
        float gs4 = gr[12], gs5 = gr[13];
        float E0 = fmaxf(acc[m][0][r] + bz[0], 0.f);
        float E1 = fmaxf(acc[m][1][r] + bz[1], 0.f);
        float E2 = fmaxf(acc[m][2][r] + bz[2], 0.f);
        float E3 = fmaxf(acc[m][3][r] + bz[3], 0.f);
        float E4 = fmaxf(acc[m][4][r] + bz[4], 0.f);
        float E5 = fmaxf(acc[m][5][r] + bz[5], 0.f);
        float o0 = ga[0] * E0 + ga[1] * E1 + ga[2] * E4 + ga[3] * E5;
        float o1 = gb[0] * E2 + gb[1] * E3 + gb[2] * E4 + gb[3] * E5;
        float o2 = gc[0] * E0 + gc[1] * E1 + gc[2] * E2 + gc[3] * E3 + gs4 * E4 + gs5 * E5;
        A1[0][row * STR + u] = f2bf(o0);
        A1[1][row * STR + u] = f2bf(o1);
        v2[q][m * 4 + r] = o2;
      }
    }
  }
  __syncthreads();

  // ---- shared-branch output -> A0 (reuse); load lvl1 biases ----
#pragma unroll
  for (int q = 0; q < 2; ++q) {
    const int u = (wave + q * 8) * 16 + col;
#pragma unroll
    for (int m = 0; m < 2; ++m)
#pragma unroll
      for (int r = 0; r < 4; ++r)
        A0[(m * 16 + rq * 4 + r) * STR + u] = f2bf(v2[q][m * 4 + r]);
  }
  for (int idx = tid; idx < 1536; idx += 512)
    bias_lds[idx] = (idx < 1024) ? be_task[1024 + idx] : be_share[512 + idx - 1024];
  __syncthreads();

  // ---- level-1 gate logits (4 waves: m = wave>>1, t = wave&1) ----
  if (wave < 4) {
    const int m = wave >> 1;
    const int t = wave & 1;
    const unsigned short* pg = ws + (t ? PG1T1_OFF : PG1T0_OFF);
    f4v ag = {0.f, 0.f, 0.f, 0.f};
    for (int kc = 0; kc < 8; ++kc) {
      s8v af = ld_af(A1[t], m, kc, col, rq);
      s8v bg = *(const s8v*)&pg[(kc * 64 + lane) * 8];
      ag = __builtin_amdgcn_mfma_f32_16x16x32_bf16(af, bg, ag, 0, 0, 0);
    }
    if (col < 4) {
#pragma unroll
      for (int r = 0; r < 4; ++r)
        g_lds[(m * 16 + rq * 4 + r) * 16 + t * 4 + col] = ag[r];
    }
  }
  __syncthreads();

  // ---- level-1 softmaxes ----
  if (tid < 32) {
    float* g = &g_lds[tid * 16];
    {
      float a0 = g[0] + bg_task[8],  a1 = g[1] + bg_task[9];
      float a2 = g[2] + bg_task[10], a3 = g[3] + bg_task[11];
      float mx = fmaxf(fmaxf(a0, a1), fmaxf(a2, a3));
      float e0 = __expf(a0 - mx), e1 = __expf(a1 - mx);
      float e2 = __expf(a2 - mx), e3 = __expf(a3 - mx);
      float inv = 1.f / (e0 + e1 + e2 + e3);
      g[0] = e0 * inv; g[1] = e1 * inv; g[2] = e2 * inv; g[3] = e3 * inv;
    }
    {
      float a0 = g[4] + bg_task[12], a1 = g[5] + bg_task[13];
      float a2 = g[6] + bg_task[14], a3 = g[7] + bg_task[15];
      float mx = fmaxf(fmaxf(a0, a1), fmaxf(a2, a3));
      float e0 = __expf(a0 - mx), e1 = __expf(a1 - mx);
      float e2 = __expf(a2 - mx), e3 = __expf(a3 - mx);
      float inv = 1.f / (e0 + e1 + e2 + e3);
      g[4] = e0 * inv; g[5] = e1 * inv; g[6] = e2 * inv; g[7] = e3 * inv;
    }
  }
  __syncthreads();

  // ---- level-1 experts + combine + store ----
#pragma unroll
  for (int q = 0; q < 2; ++q) {
    const int nt = wave + q * 8;
    f4v acc[2][6];
#pragma unroll
    for (int m = 0; m < 2; ++m)
#pragma unroll
      for (int e = 0; e < 6; ++e) acc[m][e] = (f4v){0.f, 0.f, 0.f, 0.f};

    const unsigned short* pw = ws + 6 * 65536 + nt * 4096;  // lvl1 base
    s8v bfc[6];
#pragma unroll
    for (int e = 0; e < 6; ++e)
      bfc[e] = *(const s8v*)&pw[e * 65536 + lane * 8];
#pragma unroll
    for (int kc = 0; kc < 8; ++kc) {
      s8v bfn[6];
      if (kc < 7) {
#pragma unroll
        for (int e = 0; e < 6; ++e)
          bfn[e] = *(const s8v*)&pw[e * 65536 + ((kc + 1) * 64 + lane) * 8];
      }
      s8v a0f[2], a1f[2], a2f[2];
#pragma unroll
      for (int m = 0; m < 2; ++m) {
        a0f[m] = ld_af(A1[0], m, kc, col, rq);
        a1f[m] = ld_af(A1[1], m, kc, col, rq);
        a2f[m] = ld_af(A0,    m, kc, col, rq);
      }
#pragma unroll
      for (int m = 0; m < 2; ++m) {
        acc[m][0] = __builtin_amdgcn_mfma_f32_16x16x32_bf16(a0f[m], bfc[0], acc[m][0], 0, 0, 0);
        acc[m][1] = __builtin_amdgcn_mfma_f32_16x16x32_bf16(a0f[m], bfc[1], acc[m][1], 0, 0, 0);
        acc[m][2] = __builtin_amdgcn_mfma_f32_16x16x32_bf16(a1f[m], bfc[2], acc[m][2], 0, 0, 0);
        acc[m][3] = __builtin_amdgcn_mfma_f32_16x16x32_bf16(a1f[m], bfc[3], acc[m][3], 0, 0, 0);
        acc[m][4] = __builtin_amdgcn_mfma_f32_16x16x32_bf16(a2f[m], bfc[4], acc[m][4], 0, 0, 0);
        acc[m][5] = __builtin_amdgcn_mfma_f32_16x16x32_bf16(a2f[m], bfc[5], acc[m][5], 0, 0, 0);
      }
#pragma unroll
      for (int e = 0; e < 6; ++e) bfc[e] = bfn[e];
    }

    const int u = nt * 16 + col;
    float bz[6];
#pragma unroll
    for (int e = 0; e < 6; ++e) bz[e] = bias_lds[e * 256 + u];
#pragma unroll
    for (int m = 0; m < 2; ++m) {
#pragma unroll
      for (int r = 0; r < 4; ++r) {
        int row = m * 16 + rq * 4 + r;
        const float* gr = &g_lds[row * 16];
        f4v ga = *(const f4v*)&gr[0];
        f4v gb = *(const f4v*)&gr[4];
        float E0 = fmaxf(acc[m][0][r] + bz[0], 0.f);
        float E1 = fmaxf(acc[m][1][r] + bz[1], 0.f);
        float E2 = fmaxf(acc[m][2][r] + bz[2], 0.f);
        float E3 = fmaxf(acc[m][3][r] + bz[3], 0.f);
        float E4 = fmaxf(acc[m][4][r] + bz[4], 0.f);
        float E5 = fmaxf(acc[m][5][r] + bz[5], 0.f);
        float o0 = ga[0] * E0 + ga[1] * E1 + ga[2] * E4 + ga[3] * E5;
        float o1 = gb[0] * E2 + gb[1] * E3 + gb[2] * E4 + gb[3] * E5;
        out[(long)(r0 + row) * 256 + u] = o0;
        out[16777216L + (long)(r0 + row) * 256 + u] = o1;
      }
    }
  }
}

extern "C" void kernel_launch(void* const* d_in, const int* in_sizes, int n_in,
                              void* d_out, int out_size, void* d_ws, size_t ws_size,
                              hipStream_t stream) {
  const float* x        = (const float*)d_in[0];
  const float* we_task  = (const float*)d_in[1];
  const float* be_task  = (const float*)d_in[2];
  const float* we_share = (const float*)d_in[3];
  const float* be_share = (const float*)d_in[4];
  const float* wg_task  = (const float*)d_in[5];
  const float* bg_task  = (const float*)d_in[6];
  const float* wg_share = (const float*)d_in[7];
  const float* bg_share = (const float*)d_in[8];
  unsigned short* ws = (unsigned short*)d_ws;
  float* out = (float*)d_out;

  hipLaunchKernelGGL(pack_weights, dim3((TOTAL_PACK + 255) / 256), dim3(256), 0, stream,
                     we_task, we_share, wg_task, wg_share, ws);
  hipLaunchKernelGGL(ple_fused, dim3(NB / BT), dim3(512), 0, stream,
                     x, be_task, be_share, bg_task, bg_share, ws, out);
}

// Round 4
// 369.200 us; speedup vs baseline: 1.7107x; 1.0601x over previous
//
#include <hip/hip_runtime.h>

typedef short s8v __attribute__((ext_vector_type(8)));   // 8 x bf16 bits
typedef float f4v __attribute__((ext_vector_type(4)));

#define NB 65536
#define BT 64
#define STR 264            // padded ushort stride for LDS tiles
#define PW_ELEMS 786432
#define PG0_OFF  786432
#define PG1T0_OFF 790528
#define PG1T1_OFF 794624
#define TOTAL_PACK 798720

__device__ __forceinline__ unsigned short f2bf(float f) {
  unsigned u = __float_as_uint(f);
  u += 0x7FFF + ((u >> 16) & 1);           // round-to-nearest-even
  return (unsigned short)(u >> 16);
}

__global__ void pack_weights(const float* __restrict__ we_task,
                             const float* __restrict__ we_share,
                             const float* __restrict__ wg_task,
                             const float* __restrict__ wg_share,
                             unsigned short* __restrict__ ws) {
  int i = blockIdx.x * 256 + threadIdx.x;
  if (i >= TOTAL_PACK) return;
  float v = 0.f;
  if (i < PW_ELEMS) {
    int j = i & 7;
    int t = i >> 3;
    int lane = t & 63; t >>= 6;
    int kc = t & 7;    t >>= 3;
    int nt = t & 15;   t >>= 4;
    int lvl = t / 6, e = t % 6;
    int d = kc * 32 + (lane >> 4) * 8 + j;
    int u = nt * 16 + (lane & 15);
    if (e < 4) v = we_task[((lvl * 4 + e) * 256 + d) * 256 + u];
    else       v = we_share[((lvl * 2 + (e - 4)) * 256 + d) * 256 + u];
  } else {
    int gi = i - PW_ELEMS;
    int which = gi >> 12;
    int r = gi & 4095;
    int j = r & 7;
    int lane = (r >> 3) & 63;
    int kc = r >> 9;
    int d = kc * 32 + (lane >> 4) * 8 + j;
    int n = lane & 15;
    if (which == 0) {
      if (n < 4)       v = wg_task[0 * 1024 + d * 4 + n];
      else if (n < 8)  v = wg_task[1 * 1024 + d * 4 + (n - 4)];
      else if (n < 14) v = wg_share[d * 6 + (n - 8)];
    } else if (which == 1) {
      if (n < 4) v = wg_task[2 * 1024 + d * 4 + n];
    } else {
      if (n < 4) v = wg_task[3 * 1024 + d * 4 + n];
    }
  }
  ws[i] = f2bf(v);
}

__device__ __forceinline__ s8v ld_af(const unsigned short* Ab, int m, int kc,
                                     int col, int rq) {
  return *(const s8v*)&Ab[(m * 16 + col) * STR + kc * 32 + rq * 8];
}

__launch_bounds__(512, 2)
__global__ void ple_fused(const float* __restrict__ x,
                          const float* __restrict__ be_task,
                          const float* __restrict__ be_share,
                          const float* __restrict__ bg_task,
                          const float* __restrict__ bg_share,
                          const unsigned short* __restrict__ ws,
                          float* __restrict__ out) {
  __shared__ unsigned short A0[BT * STR];       // x at lvl0
  __shared__ unsigned short A1[2][BT * STR];    // lvl1 task inputs
  __shared__ unsigned short A2[BT * STR];       // lvl1 shared-branch input
  __shared__ float g_lds[BT * 16];
  __shared__ float bias_lds[6 * 256];

  const int tid  = threadIdx.x;
  const int lane = tid & 63;
  const int wave = tid >> 6;
  const int col  = lane & 15;
  const int rq   = lane >> 4;
  const int r0   = blockIdx.x * BT;

  // ---- stage x -> bf16 LDS, load lvl0 biases ----
  {
    const float* xb = x + (long)r0 * 256;
#pragma unroll
    for (int i = 0; i < 8; ++i) {
      int f = tid + i * 512;            // 4096 float4 total (64 rows x 64)
      int row = f >> 6, c4 = f & 63;
      const float4 v = *(const float4*)(xb + row * 256 + c4 * 4);
      unsigned lo = ((unsigned)f2bf(v.y) << 16) | f2bf(v.x);
      unsigned hi = ((unsigned)f2bf(v.w) << 16) | f2bf(v.z);
      *(uint2*)&A0[row * STR + c4 * 4] = make_uint2(lo, hi);
    }
    for (int idx = tid; idx < 1536; idx += 512)
      bias_lds[idx] = (idx < 1024) ? be_task[idx] : be_share[idx - 1024];
  }
  __syncthreads();

  // ---- level-0 gate logits (waves 0..3, one m-tile each) ----
  if (wave < 4) {
    const int m = wave;
    f4v ag = {0.f, 0.f, 0.f, 0.f};
    for (int kc = 0; kc < 8; ++kc) {
      s8v af = ld_af(A0, m, kc, col, rq);
      s8v bg = *(const s8v*)&ws[PG0_OFF + (kc * 64 + lane) * 8];
      ag = __builtin_amdgcn_mfma_f32_16x16x32_bf16(af, bg, ag, 0, 0, 0);
    }
#pragma unroll
    for (int r = 0; r < 4; ++r)
      g_lds[(m * 16 + rq * 4 + r) * 16 + col] = ag[r];
  }
  __syncthreads();

  // ---- level-0 softmaxes (one thread per row) ----
  if (tid < 64) {
    float* g = &g_lds[tid * 16];
    {
      float a0 = g[0] + bg_task[0], a1 = g[1] + bg_task[1];
      float a2 = g[2] + bg_task[2], a3 = g[3] + bg_task[3];
      float mx = fmaxf(fmaxf(a0, a1), fmaxf(a2, a3));
      float e0 = __expf(a0 - mx), e1 = __expf(a1 - mx);
      float e2 = __expf(a2 - mx), e3 = __expf(a3 - mx);
      float inv = 1.f / (e0 + e1 + e2 + e3);
      g[0] = e0 * inv; g[1] = e1 * inv; g[2] = e2 * inv; g[3] = e3 * inv;
    }
    {
      float a0 = g[4] + bg_task[4], a1 = g[5] + bg_task[5];
      float a2 = g[6] + bg_task[6], a3 = g[7] + bg_task[7];
      float mx = fmaxf(fmaxf(a0, a1), fmaxf(a2, a3));
      float e0 = __expf(a0 - mx), e1 = __expf(a1 - mx);
      float e2 = __expf(a2 - mx), e3 = __expf(a3 - mx);
      float inv = 1.f / (e0 + e1 + e2 + e3);
      g[4] = e0 * inv; g[5] = e1 * inv; g[6] = e2 * inv; g[7] = e3 * inv;
    }
    {
      float a[6], mx = -1e30f;
#pragma unroll
      for (int k = 0; k < 6; ++k) { a[k] = g[8 + k] + bg_share[k]; mx = fmaxf(mx, a[k]); }
      float s = 0.f;
#pragma unroll
      for (int k = 0; k < 6; ++k) { a[k] = __expf(a[k] - mx); s += a[k]; }
      float inv = 1.f / s;
#pragma unroll
      for (int k = 0; k < 6; ++k) g[8 + k] = a[k] * inv;
    }
  }
  __syncthreads();

  // ---- level-0 experts + combine (shared-branch -> A2 in LDS, no live regs) ----
#pragma unroll
  for (int q = 0; q < 2; ++q) {
    const int nt = wave + q * 8;
    f4v acc[4][6];
#pragma unroll
    for (int m = 0; m < 4; ++m)
#pragma unroll
      for (int e = 0; e < 6; ++e) acc[m][e] = (f4v){0.f, 0.f, 0.f, 0.f};

    const unsigned short* pw = ws + nt * 4096;   // lvl0: e*65536 + nt*4096
    s8v bfc[6];
#pragma unroll
    for (int e = 0; e < 6; ++e)
      bfc[e] = *(const s8v*)&pw[e * 65536 + lane * 8];
#pragma unroll
    for (int kc = 0; kc < 8; ++kc) {
      s8v bfn[6];
      if (kc < 7) {
#pragma unroll
        for (int e = 0; e < 6; ++e)
          bfn[e] = *(const s8v*)&pw[e * 65536 + ((kc + 1) * 64 + lane) * 8];
      }
      s8v af[4];
#pragma unroll
      for (int m = 0; m < 4; ++m) af[m] = ld_af(A0, m, kc, col, rq);
#pragma unroll
      for (int m = 0; m < 4; ++m)
#pragma unroll
        for (int e = 0; e < 6; ++e)
          acc[m][e] = __builtin_amdgcn_mfma_f32_16x16x32_bf16(af[m], bfc[e], acc[m][e], 0, 0, 0);
#pragma unroll
      for (int e = 0; e < 6; ++e) bfc[e] = bfn[e];
    }

    const int u = nt * 16 + col;
    float bz[6];
#pragma unroll
    for (int e = 0; e < 6; ++e) bz[e] = bias_lds[e * 256 + u];
#pragma unroll
    for (int m = 0; m < 4; ++m) {
#pragma unroll
      for (int r = 0; r < 4; ++r) {
        int row = m * 16 + rq * 4 + r;
        const float* gr = &g_lds[row * 16];
        f4v ga = *(const f4v*)&gr[0];
        f4v gb = *(const f4v*)&gr[4];
        f4v gc = *(const f4v*)&gr[8];
        float gs4 = gr[12], gs5 = gr[13];
        float E0 = fmaxf(acc[m][0][r] + bz[0], 0.f);
        float E1 = fmaxf(acc[m][1][r] + bz[1], 0.f);
        float E2 = fmaxf(acc[m][2][r] + bz[2], 0.f);
        float E3 = fmaxf(acc[m][3][r] + bz[3], 0.f);
        float E4 = fmaxf(acc[m][4][r] + bz[4], 0.f);
        float E5 = fmaxf(acc[m][5][r] + bz[5], 0.f);
        float o0 = ga[0] * E0 + ga[1] * E1 + ga[2] * E4 + ga[3] * E5;
        float o1 = gb[0] * E2 + gb[1] * E3 + gb[2] * E4 + gb[3] * E5;
        float o2 = gc[0] * E0 + gc[1] * E1 + gc[2] * E2 + gc[3] * E3 + gs4 * E4 + gs5 * E5;
        A1[0][row * STR + u] = f2bf(o0);
        A1[1][row * STR + u] = f2bf(o1);
        A2[row * STR + u]    = f2bf(o2);
      }
    }
  }
  __syncthreads();

  // ---- lvl1 biases reload (bias_lds free after L0 combine) + lvl1 gate logits ----
  for (int idx = tid; idx < 1536; idx += 512)
    bias_lds[idx] = (idx < 1024) ? be_task[1024 + idx] : be_share[512 + idx - 1024];

  {
    const int m = wave >> 1;
    const int t = wave & 1;
    const unsigned short* pg = ws + (t ? PG1T1_OFF : PG1T0_OFF);
    f4v ag = {0.f, 0.f, 0.f, 0.f};
    for (int kc = 0; kc < 8; ++kc) {
      s8v af = ld_af(A1[t], m, kc, col, rq);
      s8v bg = *(const s8v*)&pg[(kc * 64 + lane) * 8];
      ag = __builtin_amdgcn_mfma_f32_16x16x32_bf16(af, bg, ag, 0, 0, 0);
    }
    if (col < 4) {
#pragma unroll
      for (int r = 0; r < 4; ++r)
        g_lds[(m * 16 + rq * 4 + r) * 16 + t * 4 + col] = ag[r];
    }
  }
  __syncthreads();

  // ---- level-1 softmaxes ----
  if (tid < 64) {
    float* g = &g_lds[tid * 16];
    {
      float a0 = g[0] + bg_task[8],  a1 = g[1] + bg_task[9];
      float a2 = g[2] + bg_task[10], a3 = g[3] + bg_task[11];
      float mx = fmaxf(fmaxf(a0, a1), fmaxf(a2, a3));
      float e0 = __expf(a0 - mx), e1 = __expf(a1 - mx);
      float e2 = __expf(a2 - mx), e3 = __expf(a3 - mx);
      float inv = 1.f / (e0 + e1 + e2 + e3);
      g[0] = e0 * inv; g[1] = e1 * inv; g[2] = e2 * inv; g[3] = e3 * inv;
    }
    {
      float a0 = g[4] + bg_task[12], a1 = g[5] + bg_task[13];
      float a2 = g[6] + bg_task[14], a3 = g[7] + bg_task[15];
      float mx = fmaxf(fmaxf(a0, a1), fmaxf(a2, a3));
      float e0 = __expf(a0 - mx), e1 = __expf(a1 - mx);
      float e2 = __expf(a2 - mx), e3 = __expf(a3 - mx);
      float inv = 1.f / (e0 + e1 + e2 + e3);
      g[4] = e0 * inv; g[5] = e1 * inv; g[6] = e2 * inv; g[7] = e3 * inv;
    }
  }
  __syncthreads();

  // ---- level-1 experts + combine + store ----
#pragma unroll
  for (int q = 0; q < 2; ++q) {
    const int nt = wave + q * 8;
    f4v acc[4][6];
#pragma unroll
    for (int m = 0; m < 4; ++m)
#pragma unroll
      for (int e = 0; e < 6; ++e) acc[m][e] = (f4v){0.f, 0.f, 0.f, 0.f};

    const unsigned short* pw = ws + 6 * 65536 + nt * 4096;  // lvl1 base
    s8v bfc[6];
#pragma unroll
    for (int e = 0; e < 6; ++e)
      bfc[e] = *(const s8v*)&pw[e * 65536 + lane * 8];
#pragma unroll
    for (int kc = 0; kc < 8; ++kc) {
      s8v bfn[6];
      if (kc < 7) {
#pragma unroll
        for (int e = 0; e < 6; ++e)
          bfn[e] = *(const s8v*)&pw[e * 65536 + ((kc + 1) * 64 + lane) * 8];
      }
      s8v a0f[4], a1f[4], a2f[4];
#pragma unroll
      for (int m = 0; m < 4; ++m) {
        a0f[m] = ld_af(A1[0], m, kc, col, rq);
        a1f[m] = ld_af(A1[1], m, kc, col, rq);
        a2f[m] = ld_af(A2,    m, kc, col, rq);
      }
#pragma unroll
      for (int m = 0; m < 4; ++m) {
        acc[m][0] = __builtin_amdgcn_mfma_f32_16x16x32_bf16(a0f[m], bfc[0], acc[m][0], 0, 0, 0);
        acc[m][1] = __builtin_amdgcn_mfma_f32_16x16x32_bf16(a0f[m], bfc[1], acc[m][1], 0, 0, 0);
        acc[m][2] = __builtin_amdgcn_mfma_f32_16x16x32_bf16(a1f[m], bfc[2], acc[m][2], 0, 0, 0);
        acc[m][3] = __builtin_amdgcn_mfma_f32_16x16x32_bf16(a1f[m], bfc[3], acc[m][3], 0, 0, 0);
        acc[m][4] = __builtin_amdgcn_mfma_f32_16x16x32_bf16(a2f[m], bfc[4], acc[m][4], 0, 0, 0);
        acc[m][5] = __builtin_amdgcn_mfma_f32_16x16x32_bf16(a2f[m], bfc[5], acc[m][5], 0, 0, 0);
      }
#pragma unroll
      for (int e = 0; e < 6; ++e) bfc[e] = bfn[e];
    }

    const int u = nt * 16 + col;
    float bz[6];
#pragma unroll
    for (int e = 0; e < 6; ++e) bz[e] = bias_lds[e * 256 + u];
#pragma unroll
    for (int m = 0; m < 4; ++m) {
#pragma unroll
      for (int r = 0; r < 4; ++r) {
        int row = m * 16 + rq * 4 + r;
        const float* gr = &g_lds[row * 16];
        f4v ga = *(const f4v*)&gr[0];
        f4v gb = *(const f4v*)&gr[4];
        float E0 = fmaxf(acc[m][0][r] + bz[0], 0.f);
        float E1 = fmaxf(acc[m][1][r] + bz[1], 0.f);
        float E2 = fmaxf(acc[m][2][r] + bz[2], 0.f);
        float E3 = fmaxf(acc[m][3][r] + bz[3], 0.f);
        float E4 = fmaxf(acc[m][4][r] + bz[4], 0.f);
        float E5 = fmaxf(acc[m][5][r] + bz[5], 0.f);
        float o0 = ga[0] * E0 + ga[1] * E1 + ga[2] * E4 + ga[3] * E5;
        float o1 = gb[0] * E2 + gb[1] * E3 + gb[2] * E4 + gb[3] * E5;
        out[(long)(r0 + row) * 256 + u] = o0;
        out[16777216L + (long)(r0 + row) * 256 + u] = o1;
      }
    }
  }
}

extern "C" void kernel_launch(void* const* d_in, const int* in_sizes, int n_in,
                              void* d_out, int out_size, void* d_ws, size_t ws_size,
                              hipStream_t stream) {
  const float* x        = (const float*)d_in[0];
  const float* we_task  = (const float*)d_in[1];
  const float* be_task  = (const float*)d_in[2];
  const float* we_share = (const float*)d_in[3];
  const float* be_share = (const float*)d_in[4];
  const float* wg_task  = (const float*)d_in[5];
  const float* bg_task  = (const float*)d_in[6];
  const float* wg_share = (const float*)d_in[7];
  const float* bg_share = (const float*)d_in[8];
  unsigned short* ws = (unsigned short*)d_ws;
  float* out = (float*)d_out;

  hipLaunchKernelGGL(pack_weights, dim3((TOTAL_PACK + 255) / 256), dim3(256), 0, stream,
                     we_task, we_share, wg_task, wg_share, ws);
  hipLaunchKernelGGL(ple_fused, dim3(NB / BT), dim3(512), 0, stream,
                     x, be_task, be_share, bg_task, bg_share, ws, out);
}

// Round 5
// 325.993 us; speedup vs baseline: 1.9375x; 1.1325x over previous
//
#include <hip/hip_runtime.h>

typedef short s8v __attribute__((ext_vector_type(8)));    // 8 x bf16 bits
typedef float f4v __attribute__((ext_vector_type(4)));
typedef float f16v __attribute__((ext_vector_type(16)));

#define NB 65536
#define BT 64
#define STR 264            // padded ushort stride for LDS tiles
#define PW_ELEMS 786432
#define PG0_OFF  786432
#define PG1T0_OFF 790528
#define PG1T1_OFF 794624
#define TOTAL_PACK 798720

__device__ __forceinline__ unsigned short f2bf(float f) {
  unsigned u = __float_as_uint(f);
  u += 0x7FFF + ((u >> 16) & 1);           // round-to-nearest-even
  return (unsigned short)(u >> 16);
}

// Expert weights packed for 32x32x16 MFMA B-fragments:
// i = ((((lvl*6+e)*8 + nt)*16 + ks)*64 + lane)*8 + j
//   element: d = ks*16 + (lane>>5)*8 + j ; u = nt*32 + (lane&31)
// Gate weights keep the 16x16x32 layout (unchanged offsets).
__global__ void pack_weights(const float* __restrict__ we_task,
                             const float* __restrict__ we_share,
                             const float* __restrict__ wg_task,
                             const float* __restrict__ wg_share,
                             unsigned short* __restrict__ ws) {
  int i = blockIdx.x * 256 + threadIdx.x;
  if (i >= TOTAL_PACK) return;
  float v = 0.f;
  if (i < PW_ELEMS) {
    int j = i & 7;
    int t = i >> 3;
    int lane = t & 63; t >>= 6;
    int ks = t & 15;   t >>= 4;
    int nt = t & 7;    t >>= 3;
    int lvl = t / 6, e = t % 6;
    int d = ks * 16 + (lane >> 5) * 8 + j;
    int u = nt * 32 + (lane & 31);
    if (e < 4) v = we_task[((lvl * 4 + e) * 256 + d) * 256 + u];
    else       v = we_share[((lvl * 2 + (e - 4)) * 256 + d) * 256 + u];
  } else {
    int gi = i - PW_ELEMS;
    int which = gi >> 12;
    int r = gi & 4095;
    int j = r & 7;
    int lane = (r >> 3) & 63;
    int kc = r >> 9;
    int d = kc * 32 + (lane >> 4) * 8 + j;
    int n = lane & 15;
    if (which == 0) {
      if (n < 4)       v = wg_task[0 * 1024 + d * 4 + n];
      else if (n < 8)  v = wg_task[1 * 1024 + d * 4 + (n - 4)];
      else if (n < 14) v = wg_share[d * 6 + (n - 8)];
    } else if (which == 1) {
      if (n < 4) v = wg_task[2 * 1024 + d * 4 + n];
    } else {
      if (n < 4) v = wg_task[3 * 1024 + d * 4 + n];
    }
  }
  ws[i] = f2bf(v);
}

// 16x16x32 A-fragment (gates): row = lane&15, k = kc*32 + (lane>>4)*8 + j
__device__ __forceinline__ s8v ld_a16(const unsigned short* Ab, int m, int kc,
                                      int col, int rq) {
  return *(const s8v*)&Ab[(m * 16 + col) * STR + kc * 32 + rq * 8];
}

// 32x32x16 A-fragment (experts): row = lane&31, k = ks*16 + (lane>>5)*8 + j
__device__ __forceinline__ s8v ld_a32(const unsigned short* Ab, int m, int ks,
                                      int lane) {
  return *(const s8v*)&Ab[(m * 32 + (lane & 31)) * STR + ks * 16 + (lane >> 5) * 8];
}

__launch_bounds__(512, 2)
__global__ void ple_fused(const float* __restrict__ x,
                          const float* __restrict__ be_task,
                          const float* __restrict__ be_share,
                          const float* __restrict__ bg_task,
                          const float* __restrict__ bg_share,
                          const unsigned short* __restrict__ ws,
                          float* __restrict__ out) {
  __shared__ unsigned short A0[BT * STR];       // x at lvl0
  __shared__ unsigned short A1[2][BT * STR];    // lvl1 task inputs
  __shared__ unsigned short A2[BT * STR];       // lvl1 shared-branch input
  __shared__ float g_lds[BT * 16];
  __shared__ float bias_lds[6 * 256];

  const int tid  = threadIdx.x;
  const int lane = tid & 63;
  const int wave = tid >> 6;
  const int col  = lane & 15;
  const int rq   = lane >> 4;
  const int hi   = lane >> 5;
  const int r0   = blockIdx.x * BT;

  // ---- stage x -> bf16 LDS, load lvl0 biases ----
  {
    const float* xb = x + (long)r0 * 256;
#pragma unroll
    for (int i = 0; i < 8; ++i) {
      int f = tid + i * 512;            // 4096 float4 total (64 rows x 64)
      int row = f >> 6, c4 = f & 63;
      const float4 v = *(const float4*)(xb + row * 256 + c4 * 4);
      unsigned lo = ((unsigned)f2bf(v.y) << 16) | f2bf(v.x);
      unsigned hi2 = ((unsigned)f2bf(v.w) << 16) | f2bf(v.z);
      *(uint2*)&A0[row * STR + c4 * 4] = make_uint2(lo, hi2);
    }
    for (int idx = tid; idx < 1536; idx += 512)
      bias_lds[idx] = (idx < 1024) ? be_task[idx] : be_share[idx - 1024];
  }
  __syncthreads();

  // ---- level-0 gate logits (waves 0..3, one 16-row m-tile each) ----
  if (wave < 4) {
    const int m = wave;
    f4v ag = {0.f, 0.f, 0.f, 0.f};
    for (int kc = 0; kc < 8; ++kc) {
      s8v af = ld_a16(A0, m, kc, col, rq);
      s8v bg = *(const s8v*)&ws[PG0_OFF + (kc * 64 + lane) * 8];
      ag = __builtin_amdgcn_mfma_f32_16x16x32_bf16(af, bg, ag, 0, 0, 0);
    }
#pragma unroll
    for (int r = 0; r < 4; ++r)
      g_lds[(m * 16 + rq * 4 + r) * 16 + col] = ag[r];
  }
  __syncthreads();

  // ---- level-0 softmaxes (one thread per row) ----
  if (tid < 64) {
    float* g = &g_lds[tid * 16];
    {
      float a0 = g[0] + bg_task[0], a1 = g[1] + bg_task[1];
      float a2 = g[2] + bg_task[2], a3 = g[3] + bg_task[3];
      float mx = fmaxf(fmaxf(a0, a1), fmaxf(a2, a3));
      float e0 = __expf(a0 - mx), e1 = __expf(a1 - mx);
      float e2 = __expf(a2 - mx), e3 = __expf(a3 - mx);
      float inv = 1.f / (e0 + e1 + e2 + e3);
      g[0] = e0 * inv; g[1] = e1 * inv; g[2] = e2 * inv; g[3] = e3 * inv;
    }
    {
      float a0 = g[4] + bg_task[4], a1 = g[5] + bg_task[5];
      float a2 = g[6] + bg_task[6], a3 = g[7] + bg_task[7];
      float mx = fmaxf(fmaxf(a0, a1), fmaxf(a2, a3));
      float e0 = __expf(a0 - mx), e1 = __expf(a1 - mx);
      float e2 = __expf(a2 - mx), e3 = __expf(a3 - mx);
      float inv = 1.f / (e0 + e1 + e2 + e3);
      g[4] = e0 * inv; g[5] = e1 * inv; g[6] = e2 * inv; g[7] = e3 * inv;
    }
    {
      float a[6], mx = -1e30f;
#pragma unroll
      for (int k = 0; k < 6; ++k) { a[k] = g[8 + k] + bg_share[k]; mx = fmaxf(mx, a[k]); }
      float s = 0.f;
#pragma unroll
      for (int k = 0; k < 6; ++k) { a[k] = __expf(a[k] - mx); s += a[k]; }
      float inv = 1.f / s;
#pragma unroll
      for (int k = 0; k < 6; ++k) g[8 + k] = a[k] * inv;
    }
  }
  __syncthreads();

  // ---- level-0 experts (32x32x16) + combine; shared-branch -> A2 ----
  {
    const int nt = wave;                  // one 32-col tile per wave
    const int u  = nt * 32 + (lane & 31);
    float bz[6];
#pragma unroll
    for (int e = 0; e < 6; ++e) bz[e] = bias_lds[e * 256 + u];

#pragma unroll
    for (int mp = 0; mp < 2; ++mp) {
      f16v acc[6];
#pragma unroll
      for (int e = 0; e < 6; ++e) acc[e] = (f16v)(0.f);

      s8v bfc[6];
#pragma unroll
      for (int e = 0; e < 6; ++e)
        bfc[e] = *(const s8v*)&ws[(((e << 3) + nt) << 13) + lane * 8];
#pragma unroll
      for (int ks = 0; ks < 16; ++ks) {
        s8v bfn[6];
        if (ks < 15) {
#pragma unroll
          for (int e = 0; e < 6; ++e)
            bfn[e] = *(const s8v*)&ws[(((e << 3) + nt) << 13) + (ks + 1) * 512 + lane * 8];
        }
        s8v af = ld_a32(A0, mp, ks, lane);
#pragma unroll
        for (int e = 0; e < 6; ++e)
          acc[e] = __builtin_amdgcn_mfma_f32_32x32x16_bf16(af, bfc[e], acc[e], 0, 0, 0);
#pragma unroll
        for (int e = 0; e < 6; ++e) bfc[e] = bfn[e];
      }

#pragma unroll
      for (int r = 0; r < 16; ++r) {
        int row = mp * 32 + (r & 3) + 8 * (r >> 2) + 4 * hi;
        const float* gr = &g_lds[row * 16];
        f4v ga = *(const f4v*)&gr[0];
        f4v gb = *(const f4v*)&gr[4];
        f4v gc = *(const f4v*)&gr[8];
        float gs4 = gr[12], gs5 = gr[13];
        float E0 = fmaxf(acc[0][r] + bz[0], 0.f);
        float E1 = fmaxf(acc[1][r] + bz[1], 0.f);
        float E2 = fmaxf(acc[2][r] + bz[2], 0.f);
        float E3 = fmaxf(acc[3][r] + bz[3], 0.f);
        float E4 = fmaxf(acc[4][r] + bz[4], 0.f);
        float E5 = fmaxf(acc[5][r] + bz[5], 0.f);
        float o0 = ga[0] * E0 + ga[1] * E1 + ga[2] * E4 + ga[3] * E5;
        float o1 = gb[0] * E2 + gb[1] * E3 + gb[2] * E4 + gb[3] * E5;
        float o2 = gc[0] * E0 + gc[1] * E1 + gc[2] * E2 + gc[3] * E3 + gs4 * E4 + gs5 * E5;
        A1[0][row * STR + u] = f2bf(o0);
        A1[1][row * STR + u] = f2bf(o1);
        A2[row * STR + u]    = f2bf(o2);
      }
    }
  }
  __syncthreads();

  // ---- lvl1 biases reload + lvl1 gate logits (8 waves: m = wave>>1, t = wave&1) ----
  for (int idx = tid; idx < 1536; idx += 512)
    bias_lds[idx] = (idx < 1024) ? be_task[1024 + idx] : be_share[512 + idx - 1024];

  {
    const int m = wave >> 1;
    const int t = wave & 1;
    const unsigned short* pg = ws + (t ? PG1T1_OFF : PG1T0_OFF);
    f4v ag = {0.f, 0.f, 0.f, 0.f};
    for (int kc = 0; kc < 8; ++kc) {
      s8v af = ld_a16(A1[t], m, kc, col, rq);
      s8v bg = *(const s8v*)&pg[(kc * 64 + lane) * 8];
      ag = __builtin_amdgcn_mfma_f32_16x16x32_bf16(af, bg, ag, 0, 0, 0);
    }
    if (col < 4) {
#pragma unroll
      for (int r = 0; r < 4; ++r)
        g_lds[(m * 16 + rq * 4 + r) * 16 + t * 4 + col] = ag[r];
    }
  }
  __syncthreads();

  // ---- level-1 softmaxes ----
  if (tid < 64) {
    float* g = &g_lds[tid * 16];
    {
      float a0 = g[0] + bg_task[8],  a1 = g[1] + bg_task[9];
      float a2 = g[2] + bg_task[10], a3 = g[3] + bg_task[11];
      float mx = fmaxf(fmaxf(a0, a1), fmaxf(a2, a3));
      float e0 = __expf(a0 - mx), e1 = __expf(a1 - mx);
      float e2 = __expf(a2 - mx), e3 = __expf(a3 - mx);
      float inv = 1.f / (e0 + e1 + e2 + e3);
      g[0] = e0 * inv; g[1] = e1 * inv; g[2] = e2 * inv; g[3] = e3 * inv;
    }
    {
      float a0 = g[4] + bg_task[12], a1 = g[5] + bg_task[13];
      float a2 = g[6] + bg_task[14], a3 = g[7] + bg_task[15];
      float mx = fmaxf(fmaxf(a0, a1), fmaxf(a2, a3));
      float e0 = __expf(a0 - mx), e1 = __expf(a1 - mx);
      float e2 = __expf(a2 - mx), e3 = __expf(a3 - mx);
      float inv = 1.f / (e0 + e1 + e2 + e3);
      g[4] = e0 * inv; g[5] = e1 * inv; g[6] = e2 * inv; g[7] = e3 * inv;
    }
  }
  __syncthreads();

  // ---- level-1 experts (32x32x16) + combine + full-line stores ----
  {
    const int nt = wave;
    const int u  = nt * 32 + (lane & 31);
    float bz[6];
#pragma unroll
    for (int e = 0; e < 6; ++e) bz[e] = bias_lds[e * 256 + u];

#pragma unroll
    for (int mp = 0; mp < 2; ++mp) {
      f16v acc[6];
#pragma unroll
      for (int e = 0; e < 6; ++e) acc[e] = (f16v)(0.f);

      const int l1b = 6 * 8 * 8192;     // lvl1 expert base (= 6*65536)
      s8v bfc[6];
#pragma unroll
      for (int e = 0; e < 6; ++e)
        bfc[e] = *(const s8v*)&ws[l1b + (((e << 3) + nt) << 13) + lane * 8];
#pragma unroll
      for (int ks = 0; ks < 16; ++ks) {
        s8v bfn[6];
        if (ks < 15) {
#pragma unroll
          for (int e = 0; e < 6; ++e)
            bfn[e] = *(const s8v*)&ws[l1b + (((e << 3) + nt) << 13) + (ks + 1) * 512 + lane * 8];
        }
        s8v a0f = ld_a32(A1[0], mp, ks, lane);
        s8v a1f = ld_a32(A1[1], mp, ks, lane);
        s8v a2f = ld_a32(A2,    mp, ks, lane);
        acc[0] = __builtin_amdgcn_mfma_f32_32x32x16_bf16(a0f, bfc[0], acc[0], 0, 0, 0);
        acc[1] = __builtin_amdgcn_mfma_f32_32x32x16_bf16(a0f, bfc[1], acc[1], 0, 0, 0);
        acc[2] = __builtin_amdgcn_mfma_f32_32x32x16_bf16(a1f, bfc[2], acc[2], 0, 0, 0);
        acc[3] = __builtin_amdgcn_mfma_f32_32x32x16_bf16(a1f, bfc[3], acc[3], 0, 0, 0);
        acc[4] = __builtin_amdgcn_mfma_f32_32x32x16_bf16(a2f, bfc[4], acc[4], 0, 0, 0);
        acc[5] = __builtin_amdgcn_mfma_f32_32x32x16_bf16(a2f, bfc[5], acc[5], 0, 0, 0);
#pragma unroll
        for (int e = 0; e < 6; ++e) bfc[e] = bfn[e];
      }

#pragma unroll
      for (int r = 0; r < 16; ++r) {
        int row = mp * 32 + (r & 3) + 8 * (r >> 2) + 4 * hi;
        const float* gr = &g_lds[row * 16];
        f4v ga = *(const f4v*)&gr[0];
        f4v gb = *(const f4v*)&gr[4];
        float E0 = fmaxf(acc[0][r] + bz[0], 0.f);
        float E1 = fmaxf(acc[1][r] + bz[1], 0.f);
        float E2 = fmaxf(acc[2][r] + bz[2], 0.f);
        float E3 = fmaxf(acc[3][r] + bz[3], 0.f);
        float E4 = fmaxf(acc[4][r] + bz[4], 0.f);
        float E5 = fmaxf(acc[5][r] + bz[5], 0.f);
        float o0 = ga[0] * E0 + ga[1] * E1 + ga[2] * E4 + ga[3] * E5;
        float o1 = gb[0] * E2 + gb[1] * E3 + gb[2] * E4 + gb[3] * E5;
        out[(long)(r0 + row) * 256 + u] = o0;
        out[16777216L + (long)(r0 + row) * 256 + u] = o1;
      }
    }
  }
}

extern "C" void kernel_launch(void* const* d_in, const int* in_sizes, int n_in,
                              void* d_out, int out_size, void* d_ws, size_t ws_size,
                              hipStream_t stream) {
  const float* x        = (const float*)d_in[0];
  const float* we_task  = (const float*)d_in[1];
  const float* be_task  = (const float*)d_in[2];
  const float* we_share = (const float*)d_in[3];
  const float* be_share = (const float*)d_in[4];
  const float* wg_task  = (const float*)d_in[5];
  const float* bg_task  = (const float*)d_in[6];
  const float* wg_share = (const float*)d_in[7];
  const float* bg_share = (const float*)d_in[8];
  unsigned short* ws = (unsigned short*)d_ws;
  float* out = (float*)d_out;

  hipLaunchKernelGGL(pack_weights, dim3((TOTAL_PACK + 255) / 256), dim3(256), 0, stream,
                     we_task, we_share, wg_task, wg_share, ws);
  hipLaunchKernelGGL(ple_fused, dim3(NB / BT), dim3(512), 0, stream,
                     x, be_task, be_share, bg_task, bg_share, ws, out);
}